// Round 3
// baseline (390.265 us; speedup 1.0000x reference)
//
#include <hip/hip_runtime.h>
#include <hip/hip_cooperative_groups.h>
#include <cstddef>

namespace cg = cooperative_groups;

namespace {
constexpr int B_ = 8;
constexpr int N_ = 512;
constexpr int D_ = 768;
constexpr int HS_ = 64;
constexpr int M_ = B_ * N_;   // 4096 rows (b*N + n)
constexpr int E_ = 2 * HS_;   // 128
constexpr float NEGV = 1000000000000.0f;
constexpr float LOG2_10000 = 13.287712379549449f;
constexpr int PREP_BLOCKS = 768;   // 256 m-tiles x 3 fams
constexpr int EGP_TILES   = 1536;  // 8 m x 8 n x 24 (fam*8+b)
}

typedef short mfrag_t __attribute__((ext_vector_type(8)));   // 8 bf16 (4 VGPRs)
typedef short mhalf_t __attribute__((ext_vector_type(4)));   // 4 bf16 (2 VGPRs)
typedef float macc_t  __attribute__((ext_vector_type(4)));   // 4 fp32
typedef float vf4_t   __attribute__((ext_vector_type(4)));   // vector store

__device__ __forceinline__ unsigned short bft(float x) {
    union { float f; unsigned u; } c; c.f = x;
    return (unsigned short)(c.u >> 16);   // truncate (RTZ)
}
__device__ __forceinline__ unsigned short bfrne(float x) {
    union { float f; unsigned u; } c; c.f = x;
    const unsigned r = c.u + 0x7FFFu + ((c.u >> 16) & 1u);
    return (unsigned short)(r >> 16);     // round-to-nearest-even
}

// Shared-memory overlay: phase A (prep) and phase B (egp) never live at once.
struct SmemA {
    unsigned short A_lds[16][40];    // [row][k] bf16, pad 32->40
    unsigned short B_lds[128][40];   // [w1-col][k] bf16
    float hs[16][132];               // h tile (128 cols, pad)
};
struct SmemB {
    float Cs[64][68];                // QK^T tile (pad)
    float bS[12][2][64];             // staged bias slices
};
union Smem { SmemA a; SmemB b; };    // 23552 B -> 3 blocks/CU uses 70.6 KB LDS

// ---------------------------------------------------------------------------
// Phase A: h = chars @ w1^T + b1 (all 128 cols, one family, 16 rows).
// Coalesced f32 loads -> bf16 pack -> LDS -> MFMA (R1-measured structure).
//   qbf/kbf = (roped) bf16 q/k in [row][k] fragment-ready layout.
//   bias    = ((h @ w2^T) + b2) * 0.5, final, layout [b][2H][n].
// bid in [0,768): fam = bid>>8, m-tile = bid&255.
// ---------------------------------------------------------------------------
__device__ __forceinline__ void prep_phase(
    const float* __restrict__ chars,
    const float* __restrict__ w1e, const float* __restrict__ b1e,
    const float* __restrict__ w2e, const float* __restrict__ b2e,
    const float* __restrict__ w1h, const float* __restrict__ b1h,
    const float* __restrict__ w2h, const float* __restrict__ b2h,
    const float* __restrict__ w1t, const float* __restrict__ b1t,
    const float* __restrict__ w2t, const float* __restrict__ b2t,
    unsigned short* __restrict__ qbf, unsigned short* __restrict__ kbf,
    float* __restrict__ bias_e, float* __restrict__ bias_h, float* __restrict__ bias_t,
    SmemA& sa, int bid, int t)
{
    const int fam = bid >> 8;
    const int m0  = (bid & 255) * 16;
    const float* w1 = (fam == 0) ? w1e : (fam == 1) ? w1h : w1t;
    const float* b1 = (fam == 0) ? b1e : (fam == 1) ? b1h : b1t;
    const float* w2 = (fam == 0) ? w2e : (fam == 1) ? w2h : w2t;
    const float* b2 = (fam == 0) ? b2e : (fam == 1) ? b2h : b2t;
    const int H2 = (fam == 0) ? 4 : 24;   // total bias heads (2*H)
    float* bout = (fam == 0) ? bias_e : (fam == 1) ? bias_h : bias_t;
    unsigned short* qout = qbf + (size_t)fam * M_ * HS_;
    unsigned short* kout = kbf + (size_t)fam * M_ * HS_;

    const int w    = t >> 6;          // wave 0..3
    const int lane = t & 63;
    const int ml   = lane & 15;
    const int quad = lane >> 4;

    const int ar = (t >> 3) & 15;     // A row 0..15 (t<128 active)
    const int ak = (t & 7) * 4;       // A k-offset (4 floats)
    const int bc = t >> 1;            // B col 0..127
    const int bk = (t & 1) * 16;      // B k-offset (16 floats)

    const float* aptr = chars + (size_t)(m0 + ar) * D_ + ak;
    const float* bptr = w1 + (size_t)bc * D_ + bk;

    macc_t acc[2];
    acc[0] = (macc_t)0.0f; acc[1] = (macc_t)0.0f;

    float4 av, bv0, bv1, bv2, bv3;
    if (t < 128) av = *(const float4*)(aptr);
    bv0 = *(const float4*)(bptr);
    bv1 = *(const float4*)(bptr + 4);
    bv2 = *(const float4*)(bptr + 8);
    bv3 = *(const float4*)(bptr + 12);

    for (int s = 0; s < 24; ++s) {
        if (t < 128) {
            mhalf_t pa;
            pa[0] = (short)bft(av.x); pa[1] = (short)bft(av.y);
            pa[2] = (short)bft(av.z); pa[3] = (short)bft(av.w);
            *(mhalf_t*)&sa.A_lds[ar][ak] = pa;
        }
        {
            mfrag_t pb0, pb1;
            pb0[0] = (short)bft(bv0.x); pb0[1] = (short)bft(bv0.y);
            pb0[2] = (short)bft(bv0.z); pb0[3] = (short)bft(bv0.w);
            pb0[4] = (short)bft(bv1.x); pb0[5] = (short)bft(bv1.y);
            pb0[6] = (short)bft(bv1.z); pb0[7] = (short)bft(bv1.w);
            pb1[0] = (short)bft(bv2.x); pb1[1] = (short)bft(bv2.y);
            pb1[2] = (short)bft(bv2.z); pb1[3] = (short)bft(bv2.w);
            pb1[4] = (short)bft(bv3.x); pb1[5] = (short)bft(bv3.y);
            pb1[6] = (short)bft(bv3.z); pb1[7] = (short)bft(bv3.w);
            *(mfrag_t*)&sa.B_lds[bc][bk]     = pb0;
            *(mfrag_t*)&sa.B_lds[bc][bk + 8] = pb1;
        }
        __syncthreads();
        if (s < 23) {
            aptr += 32; bptr += 32;
            if (t < 128) av = *(const float4*)(aptr);
            bv0 = *(const float4*)(bptr);
            bv1 = *(const float4*)(bptr + 4);
            bv2 = *(const float4*)(bptr + 8);
            bv3 = *(const float4*)(bptr + 12);
        }
        const mfrag_t afrag = *(const mfrag_t*)&sa.A_lds[ml][quad * 8];
        #pragma unroll
        for (int f = 0; f < 2; ++f) {
            const mfrag_t bfrag = *(const mfrag_t*)&sa.B_lds[(w * 2 + f) * 16 + ml][quad * 8];
            acc[f] = __builtin_amdgcn_mfma_f32_16x16x32_bf16(afrag, bfrag, acc[f], 0, 0, 0);
        }
        __syncthreads();
    }

    // C layout: col = (w*2+f)*16 + ml, row = quad*4 + r
    #pragma unroll
    for (int f = 0; f < 2; ++f) {
        const int col = (w * 2 + f) * 16 + ml;
        const float bb1 = b1[col];
        #pragma unroll
        for (int r = 0; r < 4; ++r)
            sa.hs[quad * 4 + r][col] = acc[f][r] + bb1;
    }
    __syncthreads();

    // q/k extraction (+rope for fam 0) -> bf16 [row][k], full k range.
    // h col 4i..4i+3 (pair i = 0..31) -> q[2i],k[2i],q[2i+1],k[2i+1]
    {
        const int row = t >> 4;          // 0..15
        const int kg  = t & 15;          // 2 pairs per thread
        const float pos = (float)((m0 & 511) + row);
        unsigned short qv[4], kv[4];
        #pragma unroll
        for (int p = 0; p < 2; ++p) {
            const int i = kg * 2 + p;    // pair 0..31
            const float q0 = sa.hs[row][4 * i + 0];
            const float k0 = sa.hs[row][4 * i + 1];
            const float q1 = sa.hs[row][4 * i + 2];
            const float k1 = sa.hs[row][4 * i + 3];
            if (fam == 0) {
                const float inv = exp2f(-(float)i * (LOG2_10000 / 32.0f));
                float sn, cs;
                sincosf(pos * inv, &sn, &cs);
                qv[2 * p + 0] = bfrne(q0 * cs - q1 * sn);
                qv[2 * p + 1] = bfrne(q1 * cs + q0 * sn);
                kv[2 * p + 0] = bfrne(k0 * cs - k1 * sn);
                kv[2 * p + 1] = bfrne(k1 * cs + k0 * sn);
            } else {
                qv[2 * p + 0] = bfrne(q0);
                qv[2 * p + 1] = bfrne(q1);
                kv[2 * p + 0] = bfrne(k0);
                kv[2 * p + 1] = bfrne(k1);
            }
        }
        const size_t off = (size_t)(m0 + row) * HS_ + kg * 4;
        *(mhalf_t*)(qout + off) = *(const mhalf_t*)&qv[0];
        *(mhalf_t*)(kout + off) = *(const mhalf_t*)&kv[0];
    }

    // fused FINAL bias: row = t&15, h2 = (t>>4) + 16p; full dot over 128 e.
    {
        const int row = t & 15;
        const int h2b = t >> 4;          // 0..15
        const int bb  = m0 >> 9;
        const int nb  = (m0 & 511) + row;
        float accv[2] = {0.0f, 0.0f};
        for (int e0 = 0; e0 < 128; e0 += 16) {
            const float4 hv0 = *(const float4*)&sa.hs[row][e0];
            const float4 hv1 = *(const float4*)&sa.hs[row][e0 + 4];
            const float4 hv2 = *(const float4*)&sa.hs[row][e0 + 8];
            const float4 hv3 = *(const float4*)&sa.hs[row][e0 + 12];
            #pragma unroll
            for (int p = 0; p < 2; ++p) {
                const int h2 = h2b + 16 * p;
                if (h2 < H2) {
                    const float* wr = w2 + (size_t)h2 * E_ + e0;
                    const float4 w0  = *(const float4*)(wr);
                    const float4 w1v = *(const float4*)(wr + 4);
                    const float4 w2v = *(const float4*)(wr + 8);
                    const float4 w3v = *(const float4*)(wr + 12);
                    accv[p] += hv0.x * w0.x + hv0.y * w0.y + hv0.z * w0.z + hv0.w * w0.w
                             + hv1.x * w1v.x + hv1.y * w1v.y + hv1.z * w1v.z + hv1.w * w1v.w
                             + hv2.x * w2v.x + hv2.y * w2v.y + hv2.z * w2v.z + hv2.w * w2v.w
                             + hv3.x * w3v.x + hv3.y * w3v.y + hv3.z * w3v.z + hv3.w * w3v.w;
                }
            }
        }
        #pragma unroll
        for (int p = 0; p < 2; ++p) {
            const int h2 = h2b + 16 * p;
            if (h2 < H2)
                bout[((size_t)bb * H2 + h2) * N_ + nb] = (accv[p] + b2[h2]) * 0.5f;
        }
    }
}

// ---------------------------------------------------------------------------
// Phase B: MFMA QK^T (fragments direct from global bf16 q/k) + bias + masks.
// 64x64 tile, K=64. Bias slices staged to LDS. Non-temporal output stores.
// Leading __syncthreads protects Cs/bS (and phase-A hs) reuse across calls.
// ---------------------------------------------------------------------------
template <int H, bool TRIL>
__device__ __forceinline__ void egp_tile(
    const unsigned short* __restrict__ qf, const unsigned short* __restrict__ kf,
    const float* __restrict__ bias, const int* __restrict__ mask,
    float* __restrict__ out, int b, int m0, int n0, SmemB& sb, int t)
{
    __syncthreads();

    //   bS[hh][0][c] = bias[b][2hh  ][n0+c]  (even-head / column term)
    //   bS[hh][1][r] = bias[b][2hh+1][m0+r]  (odd-head  / row term)
    #pragma unroll
    for (int it = 0; it < (H * 128) / 256; ++it) {
        const int i   = t + it * 256;
        const int hh  = i >> 7;
        const int wh  = (i >> 6) & 1;
        const int off = i & 63;
        sb.bS[hh][wh][off] =
            bias[((size_t)b * 2 * H + 2 * hh + wh) * N_ + (wh ? m0 : n0) + off];
    }

    const int w    = t >> 6;
    const int lane = t & 63;
    const int ml   = lane & 15;
    const int quad = lane >> 4;

    macc_t acc[4];
    #pragma unroll
    for (int f = 0; f < 4; ++f) acc[f] = (macc_t)0.0f;

    const unsigned short* qrow = qf + (size_t)(b * N_ + m0 + w * 16 + ml) * HS_ + quad * 8;
    const unsigned short* krow = kf + (size_t)(b * N_ + n0 + ml) * HS_ + quad * 8;

    #pragma unroll
    for (int s = 0; s < 2; ++s) {
        const mfrag_t af = *(const mfrag_t*)(qrow + s * 32);
        #pragma unroll
        for (int f = 0; f < 4; ++f) {
            const mfrag_t bf = *(const mfrag_t*)(krow + (size_t)f * 16 * HS_ + s * 32);
            acc[f] = __builtin_amdgcn_mfma_f32_16x16x32_bf16(af, bf, acc[f], 0, 0, 0);
        }
    }

    // C layout -> LDS: row = w*16 + quad*4 + r, col = f*16 + ml  (scaled)
    #pragma unroll
    for (int f = 0; f < 4; ++f)
        #pragma unroll
        for (int r = 0; r < 4; ++r)
            sb.Cs[w * 16 + quad * 4 + r][f * 16 + ml] = acc[f][r] * 0.125f;
    __syncthreads();

    const int rq = t >> 4;   // rows m0 + 4*rq + j
    const int cq = t & 15;   // cols n0 + 4*cq + q

    float4 av[4];
    #pragma unroll
    for (int j = 0; j < 4; ++j) av[j] = *(const float4*)&sb.Cs[4 * rq + j][4 * cq];

    int mrow[4], mm[4];
    #pragma unroll
    for (int j = 0; j < 4; ++j) {
        mrow[j] = m0 + 4 * rq + j;
        mm[j]   = mask[b * N_ + mrow[j]];
    }
    const int ncol = n0 + 4 * cq;
    const int4 mnv = *(const int4*)(mask + b * N_ + ncol);
    const int mn[4] = { mnv.x, mnv.y, mnv.z, mnv.w };

    #pragma unroll
    for (int hh = 0; hh < H; ++hh) {
        const float4 be = *(const float4*)&sb.bS[hh][0][4 * cq];

        #pragma unroll
        for (int j = 0; j < 4; ++j) {
            const float bo = sb.bS[hh][1][4 * rq + j];
            const float* aj = (const float*)&av[j];
            float o[4] = { aj[0] + be.x + bo, aj[1] + be.y + bo,
                           aj[2] + be.z + bo, aj[3] + be.w + bo };
            #pragma unroll
            for (int q = 0; q < 4; ++q) {
                if (!(mm[j] & mn[q])) o[q] -= NEGV;
                if (TRIL && (ncol + q) < mrow[j]) o[q] -= NEGV;
            }
            vf4_t ov;
            ov.x = o[0]; ov.y = o[1]; ov.z = o[2]; ov.w = o[3];
            __builtin_nontemporal_store(
                ov, (vf4_t*)(out + ((size_t)(b * H + hh) * N_ + mrow[j]) * N_ + ncol));
        }
    }
}

__device__ __forceinline__ void egp_do_tile(
    int tile, const unsigned short* __restrict__ qbf,
    const unsigned short* __restrict__ kbf,
    const float* __restrict__ bias_e, const float* __restrict__ bias_h,
    const float* __restrict__ bias_t,
    const int* __restrict__ mask, float* __restrict__ out, SmemB& sb, int t)
{
    const int z   = tile >> 6;        // fam*8 + b
    const int rem = tile & 63;
    const int m0  = (rem & 7) * 64;
    const int n0  = (rem >> 3) * 64;
    const int fam = z >> 3;
    const int b   = z & 7;

    const size_t ent_sz  = (size_t)B_ * 2 * N_ * N_;
    const size_t head_sz = (size_t)B_ * 12 * N_ * N_;
    const size_t fsl = (size_t)M_ * HS_;

    if (fam == 0) {
        egp_tile<2, true>(qbf, kbf, bias_e, mask, out, b, m0, n0, sb, t);
    } else if (fam == 1) {
        egp_tile<12, false>(qbf + fsl, kbf + fsl, bias_h, mask,
                            out + ent_sz, b, m0, n0, sb, t);
    } else {
        egp_tile<12, false>(qbf + 2 * fsl, kbf + 2 * fsl, bias_t, mask,
                            out + ent_sz + head_sz, b, m0, n0, sb, t);
    }
}

// ---------------------------------------------------------------------------
// Fused cooperative kernel: prep -> grid.sync -> 2 egp tiles per block.
// 768 blocks x 256 threads, 3 blocks/CU (LDS 70.6 KB/CU, VGPR capped by
// launch_bounds so co-residency holds).
// ---------------------------------------------------------------------------
__global__ __launch_bounds__(256, 3) void fused_kernel(
    const float* __restrict__ chars, const int* __restrict__ mask,
    const float* __restrict__ w1e, const float* __restrict__ b1e,
    const float* __restrict__ w2e, const float* __restrict__ b2e,
    const float* __restrict__ w1h, const float* __restrict__ b1h,
    const float* __restrict__ w2h, const float* __restrict__ b2h,
    const float* __restrict__ w1t, const float* __restrict__ b1t,
    const float* __restrict__ w2t, const float* __restrict__ b2t,
    unsigned short* __restrict__ qbf, unsigned short* __restrict__ kbf,
    float* __restrict__ bias_e, float* __restrict__ bias_h,
    float* __restrict__ bias_t, float* __restrict__ out)
{
    __shared__ Smem sm;
    const int t   = threadIdx.x;
    const int bid = blockIdx.x;

    prep_phase(chars, w1e, b1e, w2e, b2e, w1h, b1h, w2h, b2h,
               w1t, b1t, w2t, b2t, qbf, kbf, bias_e, bias_h, bias_t,
               sm.a, bid, t);

    cg::this_grid().sync();

    #pragma unroll
    for (int i = 0; i < 2; ++i)
        egp_do_tile(bid + i * PREP_BLOCKS, qbf, kbf, bias_e, bias_h, bias_t,
                    mask, out, sm.b, t);
}

// --- fallback path (used only if cooperative launch is refused) ------------
__global__ __launch_bounds__(256) void prep_kernel(
    const float* __restrict__ chars,
    const float* __restrict__ w1e, const float* __restrict__ b1e,
    const float* __restrict__ w2e, const float* __restrict__ b2e,
    const float* __restrict__ w1h, const float* __restrict__ b1h,
    const float* __restrict__ w2h, const float* __restrict__ b2h,
    const float* __restrict__ w1t, const float* __restrict__ b1t,
    const float* __restrict__ w2t, const float* __restrict__ b2t,
    unsigned short* __restrict__ qbf, unsigned short* __restrict__ kbf,
    float* __restrict__ bias_e, float* __restrict__ bias_h, float* __restrict__ bias_t)
{
    __shared__ Smem sm;
    prep_phase(chars, w1e, b1e, w2e, b2e, w1h, b1h, w2h, b2h,
               w1t, b1t, w2t, b2t, qbf, kbf, bias_e, bias_h, bias_t,
               sm.a, blockIdx.x, threadIdx.x);
}

__global__ __launch_bounds__(256) void egp_kernel(
    const unsigned short* __restrict__ qbf, const unsigned short* __restrict__ kbf,
    const float* __restrict__ bias_e, const float* __restrict__ bias_h,
    const float* __restrict__ bias_t,
    const int* __restrict__ mask, float* __restrict__ out)
{
    __shared__ Smem sm;
    egp_do_tile(blockIdx.x, qbf, kbf, bias_e, bias_h, bias_t, mask, out,
                sm.b, threadIdx.x);
}

// ---------------------------------------------------------------------------
extern "C" void kernel_launch(void* const* d_in, const int* in_sizes, int n_in,
                              void* d_out, int out_size, void* d_ws, size_t ws_size,
                              hipStream_t stream)
{
    const float* chars = (const float*)d_in[0];
    const int*   mask  = (const int*)d_in[1];
    const float* w1e = (const float*)d_in[2];
    const float* b1e = (const float*)d_in[3];
    const float* w2e = (const float*)d_in[4];
    const float* b2e = (const float*)d_in[5];
    const float* w1h = (const float*)d_in[6];
    const float* b1h = (const float*)d_in[7];
    const float* w2h = (const float*)d_in[8];
    const float* b2h = (const float*)d_in[9];
    const float* w1t = (const float*)d_in[10];
    const float* b1t = (const float*)d_in[11];
    const float* w2t = (const float*)d_in[12];
    const float* b2t = (const float*)d_in[13];

    float* out = (float*)d_out;

    // workspace layout
    unsigned short* qbf = (unsigned short*)d_ws;               // 3*4096*64 bf16
    unsigned short* kbf = qbf + (size_t)3 * M_ * HS_;          // 3*4096*64 bf16
    float* bias_e = (float*)(kbf + (size_t)3 * M_ * HS_);      // 8*4*512  (final)
    float* bias_h = bias_e + (size_t)B_ * 4 * N_;              // 8*24*512 (final)
    float* bias_t = bias_h + (size_t)B_ * 24 * N_;             // 8*24*512 (final)

    void* kargs[] = {
        (void*)&chars, (void*)&mask,
        (void*)&w1e, (void*)&b1e, (void*)&w2e, (void*)&b2e,
        (void*)&w1h, (void*)&b1h, (void*)&w2h, (void*)&b2h,
        (void*)&w1t, (void*)&b1t, (void*)&w2t, (void*)&b2t,
        (void*)&qbf, (void*)&kbf,
        (void*)&bias_e, (void*)&bias_h, (void*)&bias_t,
        (void*)&out
    };

    const hipError_t err = hipLaunchCooperativeKernel(
        (void*)fused_kernel, dim3(PREP_BLOCKS), dim3(256), kargs, 0, stream);

    if (err != hipSuccess) {
        // Fallback: classic 2-kernel path (same device code, no grid sync).
        prep_kernel<<<dim3(PREP_BLOCKS), 256, 0, stream>>>(
            chars, w1e, b1e, w2e, b2e, w1h, b1h, w2h, b2h,
            w1t, b1t, w2t, b2t, qbf, kbf, bias_e, bias_h, bias_t);
        egp_kernel<<<dim3(EGP_TILES), 256, 0, stream>>>(
            qbf, kbf, bias_e, bias_h, bias_t, mask, out);
    }
}

// Round 4
// 286.599 us; speedup vs baseline: 1.3617x; 1.3617x over previous
//
#include <hip/hip_runtime.h>
#include <cstddef>

namespace {
constexpr int B_ = 8;
constexpr int N_ = 512;
constexpr int D_ = 768;
constexpr int HS_ = 64;
constexpr int M_ = B_ * N_;   // 4096 rows (b*N + n)
constexpr int E_ = 2 * HS_;   // 128
constexpr float NEGV = 1000000000000.0f;
constexpr float LOG2_10000 = 13.287712379549449f;
}

typedef short mfrag_t __attribute__((ext_vector_type(8)));   // 8 bf16 (4 VGPRs)
typedef short mhalf_t __attribute__((ext_vector_type(4)));   // 4 bf16 (2 VGPRs)
typedef float macc_t  __attribute__((ext_vector_type(4)));   // 4 fp32
typedef float vf4_t   __attribute__((ext_vector_type(4)));   // vector store

__device__ __forceinline__ unsigned short bft(float x) {
    union { float f; unsigned u; } c; c.f = x;
    return (unsigned short)(c.u >> 16);   // truncate (RTZ)
}
__device__ __forceinline__ unsigned short bfrne(float x) {
    union { float f; unsigned u; } c; c.f = x;
    const unsigned r = c.u + 0x7FFFu + ((c.u >> 16) & 1u);
    return (unsigned short)(r >> 16);     // round-to-nearest-even
}

// ---------------------------------------------------------------------------
// Stage 1 (MFMA): h = chars @ w1^T + b1 for ALL 128 cols of one family.
//   qbf/kbf = (roped) bf16 q/k in [row][k] fragment-ready layout, full k=64.
//   bias    = ((h @ w2^T) + b2) * 0.5, final (no partials), layout [b][2H][n].
// grid (256, 3): (16-row m-tile, fam), block 256 (4 waves). 768 blocks = 3/CU.
// (R1-measured structure; do not re-"optimize" -- the pack loop is NOT the
//  bottleneck, and direct-from-global B-fragments measured slower in R2.)
// ---------------------------------------------------------------------------
__global__ __launch_bounds__(256) void prep_kernel(
    const float* __restrict__ chars,
    const float* __restrict__ w1e, const float* __restrict__ b1e,
    const float* __restrict__ w2e, const float* __restrict__ b2e,
    const float* __restrict__ w1h, const float* __restrict__ b1h,
    const float* __restrict__ w2h, const float* __restrict__ b2h,
    const float* __restrict__ w1t, const float* __restrict__ b1t,
    const float* __restrict__ w2t, const float* __restrict__ b2t,
    unsigned short* __restrict__ qbf, unsigned short* __restrict__ kbf,
    float* __restrict__ bias_e, float* __restrict__ bias_h, float* __restrict__ bias_t)
{
    const int fam = blockIdx.y;
    const float* w1 = (fam == 0) ? w1e : (fam == 1) ? w1h : w1t;
    const float* b1 = (fam == 0) ? b1e : (fam == 1) ? b1h : b1t;
    const float* w2 = (fam == 0) ? w2e : (fam == 1) ? w2h : w2t;
    const float* b2 = (fam == 0) ? b2e : (fam == 1) ? b2h : b2t;
    const int H2 = (fam == 0) ? 4 : 24;   // total bias heads (2*H)
    float* bout = (fam == 0) ? bias_e : (fam == 1) ? bias_h : bias_t;
    unsigned short* qout = qbf + (size_t)fam * M_ * HS_;
    unsigned short* kout = kbf + (size_t)fam * M_ * HS_;
    const int m0 = blockIdx.x * 16;

    __shared__ unsigned short A_lds[16][40];    // [row][k] bf16, pad 32->40
    __shared__ unsigned short B_lds[128][40];   // [w1-col][k] bf16
    __shared__ float hs[16][132];               // full h tile (128 cols, pad)

    const int t    = threadIdx.x;
    const int w    = t >> 6;          // wave 0..3
    const int lane = t & 63;
    const int ml   = lane & 15;
    const int quad = lane >> 4;

    const int ar = (t >> 3) & 15;     // A row 0..15 (t<128 active)
    const int ak = (t & 7) * 4;       // A k-offset (4 floats)
    const int bc = t >> 1;            // B col 0..127
    const int bk = (t & 1) * 16;      // B k-offset (16 floats)

    const float* aptr = chars + (size_t)(m0 + ar) * D_ + ak;
    const float* bptr = w1 + (size_t)bc * D_ + bk;

    macc_t acc[2];
    acc[0] = (macc_t)0.0f; acc[1] = (macc_t)0.0f;

    float4 av, bv0, bv1, bv2, bv3;
    if (t < 128) av = *(const float4*)(aptr);
    bv0 = *(const float4*)(bptr);
    bv1 = *(const float4*)(bptr + 4);
    bv2 = *(const float4*)(bptr + 8);
    bv3 = *(const float4*)(bptr + 12);

    for (int s = 0; s < 24; ++s) {
        if (t < 128) {
            mhalf_t pa;
            pa[0] = (short)bft(av.x); pa[1] = (short)bft(av.y);
            pa[2] = (short)bft(av.z); pa[3] = (short)bft(av.w);
            *(mhalf_t*)&A_lds[ar][ak] = pa;
        }
        {
            mfrag_t pb0, pb1;
            pb0[0] = (short)bft(bv0.x); pb0[1] = (short)bft(bv0.y);
            pb0[2] = (short)bft(bv0.z); pb0[3] = (short)bft(bv0.w);
            pb0[4] = (short)bft(bv1.x); pb0[5] = (short)bft(bv1.y);
            pb0[6] = (short)bft(bv1.z); pb0[7] = (short)bft(bv1.w);
            pb1[0] = (short)bft(bv2.x); pb1[1] = (short)bft(bv2.y);
            pb1[2] = (short)bft(bv2.z); pb1[3] = (short)bft(bv2.w);
            pb1[4] = (short)bft(bv3.x); pb1[5] = (short)bft(bv3.y);
            pb1[6] = (short)bft(bv3.z); pb1[7] = (short)bft(bv3.w);
            *(mfrag_t*)&B_lds[bc][bk]     = pb0;
            *(mfrag_t*)&B_lds[bc][bk + 8] = pb1;
        }
        __syncthreads();
        if (s < 23) {
            aptr += 32; bptr += 32;
            if (t < 128) av = *(const float4*)(aptr);
            bv0 = *(const float4*)(bptr);
            bv1 = *(const float4*)(bptr + 4);
            bv2 = *(const float4*)(bptr + 8);
            bv3 = *(const float4*)(bptr + 12);
        }
        const mfrag_t afrag = *(const mfrag_t*)&A_lds[ml][quad * 8];
        #pragma unroll
        for (int f = 0; f < 2; ++f) {
            const mfrag_t bfrag = *(const mfrag_t*)&B_lds[(w * 2 + f) * 16 + ml][quad * 8];
            acc[f] = __builtin_amdgcn_mfma_f32_16x16x32_bf16(afrag, bfrag, acc[f], 0, 0, 0);
        }
        __syncthreads();
    }

    // C layout: col = (w*2+f)*16 + ml, row = quad*4 + r
    #pragma unroll
    for (int f = 0; f < 2; ++f) {
        const int col = (w * 2 + f) * 16 + ml;
        const float bb1 = b1[col];
        #pragma unroll
        for (int r = 0; r < 4; ++r)
            hs[quad * 4 + r][col] = acc[f][r] + bb1;
    }
    __syncthreads();

    // q/k extraction (+rope for fam 0) -> bf16 [row][k], full k range.
    // h col 4i..4i+3 (pair i = 0..31) -> q[2i],k[2i],q[2i+1],k[2i+1]
    {
        const int row = t >> 4;          // 0..15
        const int kg  = t & 15;          // 2 pairs per thread
        const float pos = (float)((m0 & 511) + row);
        unsigned short qv[4], kv[4];
        #pragma unroll
        for (int p = 0; p < 2; ++p) {
            const int i = kg * 2 + p;    // pair 0..31
            const float q0 = hs[row][4 * i + 0];
            const float k0 = hs[row][4 * i + 1];
            const float q1 = hs[row][4 * i + 2];
            const float k1 = hs[row][4 * i + 3];
            if (fam == 0) {
                const float inv = exp2f(-(float)i * (LOG2_10000 / 32.0f));
                float sn, cs;
                sincosf(pos * inv, &sn, &cs);
                qv[2 * p + 0] = bfrne(q0 * cs - q1 * sn);
                qv[2 * p + 1] = bfrne(q1 * cs + q0 * sn);
                kv[2 * p + 0] = bfrne(k0 * cs - k1 * sn);
                kv[2 * p + 1] = bfrne(k1 * cs + k0 * sn);
            } else {
                qv[2 * p + 0] = bfrne(q0);
                qv[2 * p + 1] = bfrne(q1);
                kv[2 * p + 0] = bfrne(k0);
                kv[2 * p + 1] = bfrne(k1);
            }
        }
        const size_t off = (size_t)(m0 + row) * HS_ + kg * 4;
        *(mhalf_t*)(qout + off) = *(const mhalf_t*)&qv[0];
        *(mhalf_t*)(kout + off) = *(const mhalf_t*)&kv[0];
    }

    // fused FINAL bias: row = t&15, h2 = (t>>4) + 16p; full dot over 128 e.
    {
        const int row = t & 15;
        const int h2b = t >> 4;          // 0..15
        const int bb  = m0 >> 9;
        const int nb  = (m0 & 511) + row;
        float accv[2] = {0.0f, 0.0f};
        for (int e0 = 0; e0 < 128; e0 += 16) {
            const float4 hv0 = *(const float4*)&hs[row][e0];
            const float4 hv1 = *(const float4*)&hs[row][e0 + 4];
            const float4 hv2 = *(const float4*)&hs[row][e0 + 8];
            const float4 hv3 = *(const float4*)&hs[row][e0 + 12];
            #pragma unroll
            for (int p = 0; p < 2; ++p) {
                const int h2 = h2b + 16 * p;
                if (h2 < H2) {
                    const float* wr = w2 + (size_t)h2 * E_ + e0;
                    const float4 w0  = *(const float4*)(wr);
                    const float4 w1v = *(const float4*)(wr + 4);
                    const float4 w2v = *(const float4*)(wr + 8);
                    const float4 w3v = *(const float4*)(wr + 12);
                    accv[p] += hv0.x * w0.x + hv0.y * w0.y + hv0.z * w0.z + hv0.w * w0.w
                             + hv1.x * w1v.x + hv1.y * w1v.y + hv1.z * w1v.z + hv1.w * w1v.w
                             + hv2.x * w2v.x + hv2.y * w2v.y + hv2.z * w2v.z + hv2.w * w2v.w
                             + hv3.x * w3v.x + hv3.y * w3v.y + hv3.z * w3v.z + hv3.w * w3v.w;
                }
            }
        }
        #pragma unroll
        for (int p = 0; p < 2; ++p) {
            const int h2 = h2b + 16 * p;
            if (h2 < H2)
                bout[((size_t)bb * H2 + h2) * N_ + nb] = (accv[p] + b2[h2]) * 0.5f;
        }
    }
}

// ---------------------------------------------------------------------------
// Stage 2: MFMA QK^T (fragments direct from global bf16 q/k) + bias + masks.
// grid (8, 8, 24): (m-tile, n-tile, fam*8+b), block 256. 64x64 tile, K=64.
// Bias slices staged to LDS once per block; non-temporal output stores
// (measured best R0/R2). Standalone kernel => ~6 blocks/CU occupancy, which
// the fused R3 experiment proved is what keeps the store stream at BW.
// ---------------------------------------------------------------------------
template <int H, bool TRIL>
__device__ __forceinline__ void egp_tile(
    const unsigned short* __restrict__ qf, const unsigned short* __restrict__ kf,
    const float* __restrict__ bias, const int* __restrict__ mask,
    float* __restrict__ out, int b, int m0, int n0,
    float (*Cs)[68], float (*bS)[2][64], int t)
{
    // Stage bias slices for this tile:
    //   bS[hh][0][c] = bias[b][2hh  ][n0+c]  (even-head / column term)
    //   bS[hh][1][r] = bias[b][2hh+1][m0+r]  (odd-head  / row term)
    #pragma unroll
    for (int it = 0; it < (H * 128) / 256; ++it) {
        const int i   = t + it * 256;
        const int hh  = i >> 7;
        const int wh  = (i >> 6) & 1;
        const int off = i & 63;
        bS[hh][wh][off] =
            bias[((size_t)b * 2 * H + 2 * hh + wh) * N_ + (wh ? m0 : n0) + off];
    }

    const int w    = t >> 6;
    const int lane = t & 63;
    const int ml   = lane & 15;
    const int quad = lane >> 4;

    macc_t acc[4];
    #pragma unroll
    for (int f = 0; f < 4; ++f) acc[f] = (macc_t)0.0f;

    const unsigned short* qrow = qf + (size_t)(b * N_ + m0 + w * 16 + ml) * HS_ + quad * 8;
    const unsigned short* krow = kf + (size_t)(b * N_ + n0 + ml) * HS_ + quad * 8;

    #pragma unroll
    for (int s = 0; s < 2; ++s) {
        const mfrag_t af = *(const mfrag_t*)(qrow + s * 32);
        #pragma unroll
        for (int f = 0; f < 4; ++f) {
            const mfrag_t bf = *(const mfrag_t*)(krow + (size_t)f * 16 * HS_ + s * 32);
            acc[f] = __builtin_amdgcn_mfma_f32_16x16x32_bf16(af, bf, acc[f], 0, 0, 0);
        }
    }

    // C layout -> LDS: row = w*16 + quad*4 + r, col = f*16 + ml  (scaled)
    #pragma unroll
    for (int f = 0; f < 4; ++f)
        #pragma unroll
        for (int r = 0; r < 4; ++r)
            Cs[w * 16 + quad * 4 + r][f * 16 + ml] = acc[f][r] * 0.125f;
    __syncthreads();

    const int rq = t >> 4;   // rows m0 + 4*rq + j
    const int cq = t & 15;   // cols n0 + 4*cq + q

    float4 av[4];
    #pragma unroll
    for (int j = 0; j < 4; ++j) av[j] = *(const float4*)&Cs[4 * rq + j][4 * cq];

    int mrow[4], mm[4];
    #pragma unroll
    for (int j = 0; j < 4; ++j) {
        mrow[j] = m0 + 4 * rq + j;
        mm[j]   = mask[b * N_ + mrow[j]];
    }
    const int ncol = n0 + 4 * cq;
    const int4 mnv = *(const int4*)(mask + b * N_ + ncol);
    const int mn[4] = { mnv.x, mnv.y, mnv.z, mnv.w };

    #pragma unroll
    for (int hh = 0; hh < H; ++hh) {
        const float4 be = *(const float4*)&bS[hh][0][4 * cq];

        #pragma unroll
        for (int j = 0; j < 4; ++j) {
            const float bo = bS[hh][1][4 * rq + j];
            const float* aj = (const float*)&av[j];
            float o[4] = { aj[0] + be.x + bo, aj[1] + be.y + bo,
                           aj[2] + be.z + bo, aj[3] + be.w + bo };
            #pragma unroll
            for (int q = 0; q < 4; ++q) {
                if (!(mm[j] & mn[q])) o[q] -= NEGV;
                if (TRIL && (ncol + q) < mrow[j]) o[q] -= NEGV;
            }
            vf4_t ov;
            ov.x = o[0]; ov.y = o[1]; ov.z = o[2]; ov.w = o[3];
            __builtin_nontemporal_store(
                ov, (vf4_t*)(out + ((size_t)(b * H + hh) * N_ + mrow[j]) * N_ + ncol));
        }
    }
}

__global__ __launch_bounds__(256) void egp_all_kernel(
    const unsigned short* __restrict__ qbf, const unsigned short* __restrict__ kbf,
    const float* __restrict__ bias_e, const float* __restrict__ bias_h,
    const float* __restrict__ bias_t,
    const int* __restrict__ mask, float* __restrict__ out)
{
    __shared__ float Cs[64][68];
    __shared__ float bS[12][2][64];

    const int t   = threadIdx.x;
    const int m0  = blockIdx.x * 64;
    const int n0  = blockIdx.y * 64;
    const int fam = blockIdx.z >> 3;
    const int b   = blockIdx.z & 7;

    const size_t ent_sz  = (size_t)B_ * 2 * N_ * N_;
    const size_t head_sz = (size_t)B_ * 12 * N_ * N_;
    const size_t fsl = (size_t)M_ * HS_;

    if (fam == 0) {
        egp_tile<2, true>(qbf, kbf, bias_e, mask, out, b, m0, n0, Cs, bS, t);
    } else if (fam == 1) {
        egp_tile<12, false>(qbf + fsl, kbf + fsl, bias_h, mask,
                            out + ent_sz, b, m0, n0, Cs, bS, t);
    } else {
        egp_tile<12, false>(qbf + 2 * fsl, kbf + 2 * fsl, bias_t, mask,
                            out + ent_sz + head_sz, b, m0, n0, Cs, bS, t);
    }
}

// ---------------------------------------------------------------------------
extern "C" void kernel_launch(void* const* d_in, const int* in_sizes, int n_in,
                              void* d_out, int out_size, void* d_ws, size_t ws_size,
                              hipStream_t stream)
{
    const float* chars = (const float*)d_in[0];
    const int*   mask  = (const int*)d_in[1];
    const float* w1e = (const float*)d_in[2];
    const float* b1e = (const float*)d_in[3];
    const float* w2e = (const float*)d_in[4];
    const float* b2e = (const float*)d_in[5];
    const float* w1h = (const float*)d_in[6];
    const float* b1h = (const float*)d_in[7];
    const float* w2h = (const float*)d_in[8];
    const float* b2h = (const float*)d_in[9];
    const float* w1t = (const float*)d_in[10];
    const float* b1t = (const float*)d_in[11];
    const float* w2t = (const float*)d_in[12];
    const float* b2t = (const float*)d_in[13];

    float* out = (float*)d_out;

    // workspace layout
    unsigned short* qbf = (unsigned short*)d_ws;               // 3*4096*64 bf16
    unsigned short* kbf = qbf + (size_t)3 * M_ * HS_;          // 3*4096*64 bf16
    float* bias_e = (float*)(kbf + (size_t)3 * M_ * HS_);      // 8*4*512  (final)
    float* bias_h = bias_e + (size_t)B_ * 4 * N_;              // 8*24*512 (final)
    float* bias_t = bias_h + (size_t)B_ * 24 * N_;             // 8*24*512 (final)

    prep_kernel<<<dim3(256, 3), 256, 0, stream>>>(
        chars, w1e, b1e, w2e, b2e, w1h, b1h, w2h, b2h, w1t, b1t, w2t, b2t,
        qbf, kbf, bias_e, bias_h, bias_t);

    egp_all_kernel<<<dim3(8, 8, 24), 256, 0, stream>>>(
        qbf, kbf, bias_e, bias_h, bias_t, mask, out);
}

// Round 5
// 276.257 us; speedup vs baseline: 1.4127x; 1.0374x over previous
//
#include <hip/hip_runtime.h>
#include <cstddef>

namespace {
constexpr int B_ = 8;
constexpr int N_ = 512;
constexpr int D_ = 768;
constexpr int HS_ = 64;
constexpr int M_ = B_ * N_;   // 4096 rows (b*N + n)
constexpr int E_ = 2 * HS_;   // 128
constexpr float NEGV = 1000000000000.0f;
constexpr float LOG2_10000 = 13.287712379549449f;
}

typedef short mfrag_t __attribute__((ext_vector_type(8)));   // 8 bf16 (4 VGPRs)
typedef short mhalf_t __attribute__((ext_vector_type(4)));   // 4 bf16 (2 VGPRs)
typedef float macc_t  __attribute__((ext_vector_type(4)));   // 4 fp32
typedef float vf4_t   __attribute__((ext_vector_type(4)));   // clang vector for nt-store

__device__ __forceinline__ unsigned short bft(float x) {
    union { float f; unsigned u; } c; c.f = x;
    return (unsigned short)(c.u >> 16);   // truncate (RTZ)
}
__device__ __forceinline__ unsigned short bfrne(float x) {
    union { float f; unsigned u; } c; c.f = x;
    const unsigned r = c.u + 0x7FFFu + ((c.u >> 16) & 1u);
    return (unsigned short)(r >> 16);     // round-to-nearest-even
}

// ---------------------------------------------------------------------------
// Stage 1 (MFMA): h = chars @ w1^T + b1 (LDS only);
//   bias partial = (h_half @ w2_half^T [+ b2])*0.5  (fused, 2 halves summed in egp);
//   qbf/kbf = roped bf16 q/k in [row][k] fragment-ready layout (k-half per block).
// grid (128, 6): (m-tile, half + 2*fam), block 256 (4 waves).
// Tile M=32, Ncols=64 (half of E), KB=32. 768 blocks = 3/CU for latency hiding.
// (R0-measured best structure: 12 packed floats/thread/step, 16 KB LDS/block.
//  Do NOT widen to 128-col tiles: measured +~9 us (R1/R4 ratio analysis).)
// ---------------------------------------------------------------------------
__global__ __launch_bounds__(256) void prep_kernel(
    const float* __restrict__ chars,
    const float* __restrict__ w1e, const float* __restrict__ b1e,
    const float* __restrict__ w2e, const float* __restrict__ b2e,
    const float* __restrict__ w1h, const float* __restrict__ b1h,
    const float* __restrict__ w2h, const float* __restrict__ b2h,
    const float* __restrict__ w1t, const float* __restrict__ b1t,
    const float* __restrict__ w2t, const float* __restrict__ b2t,
    unsigned short* __restrict__ qbf, unsigned short* __restrict__ kbf,
    float* __restrict__ bias_e, float* __restrict__ bias_h, float* __restrict__ bias_t)
{
    const int fam  = blockIdx.y >> 1;
    const int half = blockIdx.y & 1;
    const float* w1 = (fam == 0) ? w1e : (fam == 1) ? w1h : w1t;
    const float* b1 = (fam == 0) ? b1e : (fam == 1) ? b1h : b1t;
    const float* w2 = (fam == 0) ? w2e : (fam == 1) ? w2h : w2t;
    const float* b2 = (fam == 0) ? b2e : (fam == 1) ? b2h : b2t;
    const int H2 = (fam == 0) ? 4 : 24;
    // bias partial buffers: [half][b][h2][n] per family
    float* bout = ((fam == 0) ? bias_e : (fam == 1) ? bias_h : bias_t)
                  + (size_t)half * B_ * H2 * N_;
    unsigned short* qout = qbf + (size_t)fam * M_ * HS_;
    unsigned short* kout = kbf + (size_t)fam * M_ * HS_;
    const int m0 = blockIdx.x * 32;
    const int c0 = half * 64;          // global w1-col base of this block

    __shared__ unsigned short A_lds[32][40];   // [row][k], pad 32->40
    __shared__ unsigned short B_lds[64][40];   // [col(n) local][k]
    __shared__ float hs[32][68];               // h half-tile (local cols 0..63)

    const int t    = threadIdx.x;
    const int w    = t >> 6;          // wave 0..3
    const int lane = t & 63;
    const int ml   = lane & 15;
    const int quad = lane >> 4;
    const int wr16 = (w & 1) * 16;    // wave row strip
    const int wc32 = (w >> 1) * 32;   // wave col group (local)

    const int ar = t >> 3;            // A row 0..31
    const int ak = (t & 7) * 4;       // A k-offset (4 floats)
    const int bc = t >> 2;            // B local col 0..63
    const int bk = (t & 3) * 8;       // B k-offset (8 floats)

    const float* aptr = chars + (size_t)(m0 + ar) * D_ + ak;
    const float* bptr = w1 + (size_t)(c0 + bc) * D_ + bk;

    macc_t acc[2];
    acc[0] = (macc_t)0.0f; acc[1] = (macc_t)0.0f;

    float4 av0 = *(const float4*)(aptr);
    float4 bv0 = *(const float4*)(bptr);
    float4 bv1 = *(const float4*)(bptr + 4);

    for (int s = 0; s < 24; ++s) {
        {
            mhalf_t pa;
            pa[0] = (short)bft(av0.x); pa[1] = (short)bft(av0.y);
            pa[2] = (short)bft(av0.z); pa[3] = (short)bft(av0.w);
            *(mhalf_t*)&A_lds[ar][ak] = pa;
            mfrag_t pb;
            pb[0] = (short)bft(bv0.x); pb[1] = (short)bft(bv0.y);
            pb[2] = (short)bft(bv0.z); pb[3] = (short)bft(bv0.w);
            pb[4] = (short)bft(bv1.x); pb[5] = (short)bft(bv1.y);
            pb[6] = (short)bft(bv1.z); pb[7] = (short)bft(bv1.w);
            *(mfrag_t*)&B_lds[bc][bk] = pb;
        }
        __syncthreads();
        if (s < 23) {
            aptr += 32; bptr += 32;
            av0 = *(const float4*)(aptr);
            bv0 = *(const float4*)(bptr);
            bv1 = *(const float4*)(bptr + 4);
        }
        const mfrag_t afrag = *(const mfrag_t*)&A_lds[wr16 + ml][quad * 8];
        #pragma unroll
        for (int f = 0; f < 2; ++f) {
            const mfrag_t bfrag = *(const mfrag_t*)&B_lds[wc32 + f * 16 + ml][quad * 8];
            acc[f] = __builtin_amdgcn_mfma_f32_16x16x32_bf16(afrag, bfrag, acc[f], 0, 0, 0);
        }
        __syncthreads();
    }

    // C layout: local col = wc32 + f*16 + ml, row = wr16 + quad*4 + r
    #pragma unroll
    for (int f = 0; f < 2; ++f) {
        const int col = wc32 + f * 16 + ml;
        const float bb1 = b1[c0 + col];
        #pragma unroll
        for (int r = 0; r < 4; ++r)
            hs[wr16 + quad * 4 + r][col] = acc[f][r] + bb1;
    }
    __syncthreads();

    // q/k extraction (+rope for fam 0) -> bf16 [row][k], k-range [half*32, +32).
    // local h col 4i..4i+3 (i = local pair idx 0..15) -> q[2i],k[2i],q[2i+1],k[2i+1]
    {
        const int row = t >> 3;          // 0..31
        const int kg  = t & 7;           // 2 pairs per thread
        const float pos = (float)((m0 & 511) + row);
        unsigned short qv[4], kv[4];
        #pragma unroll
        for (int p = 0; p < 2; ++p) {
            const int il = kg * 2 + p;   // local pair 0..15
            const float q0 = hs[row][4 * il + 0];
            const float k0 = hs[row][4 * il + 1];
            const float q1 = hs[row][4 * il + 2];
            const float k1 = hs[row][4 * il + 3];
            if (fam == 0) {
                const int ig = half * 16 + il;
                const float inv = exp2f(-(float)ig * (LOG2_10000 / 32.0f));
                float sn, cs;
                sincosf(pos * inv, &sn, &cs);
                qv[2 * p + 0] = bfrne(q0 * cs - q1 * sn);
                qv[2 * p + 1] = bfrne(q1 * cs + q0 * sn);
                kv[2 * p + 0] = bfrne(k0 * cs - k1 * sn);
                kv[2 * p + 1] = bfrne(k1 * cs + k0 * sn);
            } else {
                qv[2 * p + 0] = bfrne(q0);
                qv[2 * p + 1] = bfrne(q1);
                kv[2 * p + 0] = bfrne(k0);
                kv[2 * p + 1] = bfrne(k1);
            }
        }
        const size_t off = (size_t)(m0 + row) * HS_ + half * 32 + kg * 4;
        *(mhalf_t*)(qout + off) = *(const mhalf_t*)&qv[0];
        *(mhalf_t*)(kout + off) = *(const mhalf_t*)&kv[0];
    }

    // fused partial bias: row = t&31, heads h2 = (t>>5) + 8p; dot over 64 local e.
    {
        const int row = t & 31;
        const int h2b = t >> 5;          // 0..7
        const int bb  = m0 >> 9;
        const int nb  = (m0 & 511) + row;
        float accv[3] = {0, 0, 0};
        for (int e0 = 0; e0 < 64; e0 += 16) {
            float4 hv0 = *(const float4*)&hs[row][e0];
            float4 hv1 = *(const float4*)&hs[row][e0 + 4];
            float4 hv2 = *(const float4*)&hs[row][e0 + 8];
            float4 hv3 = *(const float4*)&hs[row][e0 + 12];
            int p = 0;
            for (int h2 = h2b; h2 < H2; h2 += 8, ++p) {
                const float* wr = w2 + (size_t)h2 * E_ + c0 + e0;
                const float4 w0 = *(const float4*)(wr);
                const float4 w1v = *(const float4*)(wr + 4);
                const float4 w2v = *(const float4*)(wr + 8);
                const float4 w3v = *(const float4*)(wr + 12);
                accv[p] += hv0.x * w0.x + hv0.y * w0.y + hv0.z * w0.z + hv0.w * w0.w
                         + hv1.x * w1v.x + hv1.y * w1v.y + hv1.z * w1v.z + hv1.w * w1v.w
                         + hv2.x * w2v.x + hv2.y * w2v.y + hv2.z * w2v.z + hv2.w * w2v.w
                         + hv3.x * w3v.x + hv3.y * w3v.y + hv3.z * w3v.z + hv3.w * w3v.w;
            }
        }
        int p = 0;
        for (int h2 = h2b; h2 < H2; h2 += 8, ++p) {
            const float bterm = (half == 0) ? b2[h2] : 0.0f;
            bout[((size_t)bb * H2 + h2) * N_ + nb] = (accv[p] + bterm) * 0.5f;
        }
    }
}

// ---------------------------------------------------------------------------
// Stage 2: MFMA QK^T (fragments direct from global bf16 q/k) + bias + masks.
// grid (8, 8, 24): (m-tile, n-tile, fam*8+b), block 256. 64x64 tile, K=64.
// bias = sum of the two half-partials. Output stores non-temporal.
// ---------------------------------------------------------------------------
template <int H, bool TRIL>
__device__ __forceinline__ void egp_tile(
    const unsigned short* __restrict__ qf, const unsigned short* __restrict__ kf,
    const float* __restrict__ bias0, const float* __restrict__ bias1,
    const int* __restrict__ mask,
    float* __restrict__ out, int b, int m0, int n0, float (*Cs)[68], int t)
{
    const int w    = t >> 6;
    const int lane = t & 63;
    const int ml   = lane & 15;
    const int quad = lane >> 4;

    macc_t acc[4];
    #pragma unroll
    for (int f = 0; f < 4; ++f) acc[f] = (macc_t)0.0f;

    const unsigned short* qrow = qf + (size_t)(b * N_ + m0 + w * 16 + ml) * HS_ + quad * 8;
    const unsigned short* krow = kf + (size_t)(b * N_ + n0 + ml) * HS_ + quad * 8;

    #pragma unroll
    for (int s = 0; s < 2; ++s) {
        const mfrag_t af = *(const mfrag_t*)(qrow + s * 32);
        #pragma unroll
        for (int f = 0; f < 4; ++f) {
            const mfrag_t bf = *(const mfrag_t*)(krow + (size_t)f * 16 * HS_ + s * 32);
            acc[f] = __builtin_amdgcn_mfma_f32_16x16x32_bf16(af, bf, acc[f], 0, 0, 0);
        }
    }

    // C layout -> LDS: row = w*16 + quad*4 + r, col = f*16 + ml  (scaled)
    #pragma unroll
    for (int f = 0; f < 4; ++f)
        #pragma unroll
        for (int r = 0; r < 4; ++r)
            Cs[w * 16 + quad * 4 + r][f * 16 + ml] = acc[f][r] * 0.125f;
    __syncthreads();

    const int rq = t >> 4;   // rows m0 + 4*rq + j
    const int cq = t & 15;   // cols n0 + 4*cq + q

    float4 av[4];
    #pragma unroll
    for (int j = 0; j < 4; ++j) av[j] = *(const float4*)&Cs[4 * rq + j][4 * cq];

    int mrow[4], mm[4];
    #pragma unroll
    for (int j = 0; j < 4; ++j) {
        mrow[j] = m0 + 4 * rq + j;
        mm[j]   = mask[b * N_ + mrow[j]];
    }
    const int ncol = n0 + 4 * cq;
    const int4 mnv = *(const int4*)(mask + b * N_ + ncol);
    const int mn[4] = { mnv.x, mnv.y, mnv.z, mnv.w };

    #pragma unroll
    for (int hh = 0; hh < H; ++hh) {
        const size_t be_idx = ((size_t)b * 2 * H + 2 * hh) * N_ + ncol;
        const float4 be0 = *(const float4*)(bias0 + be_idx);
        const float4 be1 = *(const float4*)(bias1 + be_idx);
        const float4 be = make_float4(be0.x + be1.x, be0.y + be1.y,
                                      be0.z + be1.z, be0.w + be1.w);
        float bo[4];
        #pragma unroll
        for (int j = 0; j < 4; ++j) {
            const size_t bo_idx = ((size_t)b * 2 * H + 2 * hh + 1) * N_ + mrow[j];
            bo[j] = bias0[bo_idx] + bias1[bo_idx];
        }

        #pragma unroll
        for (int j = 0; j < 4; ++j) {
            const float* aj = (const float*)&av[j];
            float o[4] = { aj[0] + be.x + bo[j], aj[1] + be.y + bo[j],
                           aj[2] + be.z + bo[j], aj[3] + be.w + bo[j] };
            #pragma unroll
            for (int q = 0; q < 4; ++q) {
                if (!(mm[j] & mn[q])) o[q] -= NEGV;
                if (TRIL && (ncol + q) < mrow[j]) o[q] -= NEGV;
            }
            vf4_t ov;
            ov.x = o[0]; ov.y = o[1]; ov.z = o[2]; ov.w = o[3];
            __builtin_nontemporal_store(
                ov, (vf4_t*)(out + ((size_t)(b * H + hh) * N_ + mrow[j]) * N_ + ncol));
        }
    }
}

__global__ __launch_bounds__(256) void egp_all_kernel(
    const unsigned short* __restrict__ qbf, const unsigned short* __restrict__ kbf,
    const float* __restrict__ bias_e, const float* __restrict__ bias_h,
    const float* __restrict__ bias_t,
    const int* __restrict__ mask, float* __restrict__ out)
{
    __shared__ float Cs[64][68];

    const int t   = threadIdx.x;
    const int m0  = blockIdx.x * 64;
    const int n0  = blockIdx.y * 64;
    const int fam = blockIdx.z >> 3;
    const int b   = blockIdx.z & 7;

    const size_t ent_sz  = (size_t)B_ * 2 * N_ * N_;
    const size_t head_sz = (size_t)B_ * 12 * N_ * N_;
    const size_t fsl = (size_t)M_ * HS_;
    const size_t ehalf = (size_t)B_ * 4 * N_;    // ent partial-buffer stride
    const size_t hhalf = (size_t)B_ * 24 * N_;   // head/tail partial-buffer stride

    if (fam == 0) {
        egp_tile<2, true>(qbf, kbf, bias_e, bias_e + ehalf, mask, out, b, m0, n0, Cs, t);
    } else if (fam == 1) {
        egp_tile<12, false>(qbf + fsl, kbf + fsl, bias_h, bias_h + hhalf, mask,
                            out + ent_sz, b, m0, n0, Cs, t);
    } else {
        egp_tile<12, false>(qbf + 2 * fsl, kbf + 2 * fsl, bias_t, bias_t + hhalf, mask,
                            out + ent_sz + head_sz, b, m0, n0, Cs, t);
    }
}

// ---------------------------------------------------------------------------
extern "C" void kernel_launch(void* const* d_in, const int* in_sizes, int n_in,
                              void* d_out, int out_size, void* d_ws, size_t ws_size,
                              hipStream_t stream)
{
    const float* chars = (const float*)d_in[0];
    const int*   mask  = (const int*)d_in[1];
    const float* w1e = (const float*)d_in[2];
    const float* b1e = (const float*)d_in[3];
    const float* w2e = (const float*)d_in[4];
    const float* b2e = (const float*)d_in[5];
    const float* w1h = (const float*)d_in[6];
    const float* b1h = (const float*)d_in[7];
    const float* w2h = (const float*)d_in[8];
    const float* b2h = (const float*)d_in[9];
    const float* w1t = (const float*)d_in[10];
    const float* b1t = (const float*)d_in[11];
    const float* w2t = (const float*)d_in[12];
    const float* b2t = (const float*)d_in[13];

    float* out = (float*)d_out;

    // workspace layout
    unsigned short* qbf = (unsigned short*)d_ws;               // 3*4096*64 bf16
    unsigned short* kbf = qbf + (size_t)3 * M_ * HS_;          // 3*4096*64 bf16
    float* bias_e = (float*)(kbf + (size_t)3 * M_ * HS_);      // 2 halves * 8*4*512
    float* bias_h = bias_e + (size_t)2 * B_ * 4 * N_;          // 2 halves * 8*24*512
    float* bias_t = bias_h + (size_t)2 * B_ * 24 * N_;         // 2 halves * 8*24*512

    prep_kernel<<<dim3(128, 6), 256, 0, stream>>>(
        chars, w1e, b1e, w2e, b2e, w1h, b1h, w2h, b2h, w1t, b1t, w2t, b2t,
        qbf, kbf, bias_e, bias_h, bias_t);

    egp_all_kernel<<<dim3(8, 8, 24), 256, 0, stream>>>(
        qbf, kbf, bias_e, bias_h, bias_t, mask, out);
}